// Round 16
// baseline (255.782 us; speedup 1.0000x reference)
//
#include <hip/hip_runtime.h>

#define SEQ 4096

typedef short bf16x8 __attribute__((ext_vector_type(8)));
typedef float f32x4 __attribute__((ext_vector_type(4)));
typedef unsigned short u16x4 __attribute__((ext_vector_type(4)));

#define MFMA16(a, b, c) __builtin_amdgcn_mfma_f32_16x16x32_bf16(a, b, c, 0, 0, 0)

static __device__ __forceinline__ unsigned short f2bf(float f) {
  unsigned int u = __float_as_uint(f);
  return (unsigned short)((u + 0x7FFFu + ((u >> 16) & 1u)) >> 16);
}

// ---------------------------------------------------------------------------
// Projection for a PAIR RANGE [p0, p0+np) — chunked so Q|K|Vt fit in ws_size
// (ws_size < 16 MiB on this harness; the original 24 MiB layout overran it and
// corrupted the pristine-input arena => post-timing divergence).
// grid (np*64, 3): blockIdx.x = pl*64 + ntile, blockIdx.y = mode (0=Q,1=K,2=V).
// 256 threads: t = sub*64 + dd; sub in [0,4) covers tokens [sub*16, sub*16+16).
// Accumulation (bias + c-ascending FMA) is statement-identical to the proven
// proj => bitwise-same Q/K/V as the run that passed the first check at 3.9e-3.
//   Q,K row-major  [pl][n][dd];   V transposed [pl][dd][n].
// ---------------------------------------------------------------------------
__global__ __launch_bounds__(256) void proj_tile(
    const float* __restrict__ x, const float* __restrict__ y,
    const float* __restrict__ Wq, const float* __restrict__ bq,
    const float* __restrict__ Wk, const float* __restrict__ bk,
    const float* __restrict__ Wv, const float* __restrict__ bv,
    unsigned short* __restrict__ Qc, unsigned short* __restrict__ Kc,
    unsigned short* __restrict__ Vc, int p0)
{
  __shared__ float xt[64][64];          // [channel][token]

  const int mode  = blockIdx.y;
  const int pl    = blockIdx.x >> 6;
  const int n0    = (blockIdx.x & 63) << 6;
  const int pair  = p0 + pl;
  const int hh = pair >> 2, bb = pair & 3;
  const int t  = threadIdx.x;
  const int sub = t >> 6, dd = t & 63;

  const float* in  = (mode == 0) ? x : y;
  const float* W   = (mode == 0) ? Wq : (mode == 1) ? Wk : Wv;
  const float* bia = (mode == 0) ? bq : (mode == 1) ? bk : bv;

  // stage input tile: 64 channels x 64 tokens of batch bb (coalesced)
#pragma unroll
  for (int i = 0; i < 16; ++i) {
    int e = t + (i << 8);
    int c = e >> 6, n = e & 63;
    xt[c][n] = in[((size_t)(bb * 64 + c)) * SEQ + n0 + n];
  }

  // weight row o = hh*64 + dd (4 subs redundantly load the same row; L2-hot)
  float w[64];
#pragma unroll
  for (int i = 0; i < 16; ++i) {
    f32x4 f = *(const f32x4*)(W + ((size_t)(hh * 64 + dd)) * 64 + i * 4);
    w[i * 4 + 0] = f[0]; w[i * 4 + 1] = f[1];
    w[i * 4 + 2] = f[2]; w[i * 4 + 3] = f[3];
  }
  const float bval = bia[hh * 64 + dd];
  __syncthreads();

#pragma unroll
  for (int k4 = 0; k4 < 4; ++k4) {
    const int ng = sub * 4 + k4;          // 4 tokens per iteration
    f32x4 acc = {bval, bval, bval, bval};
#pragma unroll
    for (int c = 0; c < 64; ++c) {
      f32x4 xv = *(const f32x4*)&xt[c][ng * 4];   // uniform-address broadcast
      acc += w[c] * xv;
    }
    if (mode < 2) {
      unsigned short* outRM = (mode == 0) ? Qc : Kc;
#pragma unroll
      for (int j = 0; j < 4; ++j)
        outRM[((size_t)pl * SEQ + n0 + ng * 4 + j) * 64 + dd] = f2bf(acc[j]);
    } else {
      u16x4 pk = {f2bf(acc[0]), f2bf(acc[1]), f2bf(acc[2]), f2bf(acc[3])};
      *(u16x4*)(Vc + ((size_t)pl * 64 + dd) * SEQ + n0 + ng * 4) = pk;
    }
  }
}

// ---------------------------------------------------------------------------
// Flash attention for pair range [p0, p0+np) — core verbatim from the kernel
// that passed the first correctness check (absmax 3.9e-3).
// grid np*64: blockIdx.x = pl*64 + qtile. 4 waves x 16 q-rows.
// MFMA 16x16x32 bf16; layouts per m89; LDS XOR-swizzle (row&7)<<4.
// ---------------------------------------------------------------------------
__global__ __launch_bounds__(256) void attn_kernel(
    const unsigned short* __restrict__ Qc, const unsigned short* __restrict__ Kc,
    const unsigned short* __restrict__ Vc, float* __restrict__ out, int p0)
{
  __shared__ __align__(16) unsigned char smem[24576];
  unsigned char* ldsK = smem;            // 8 KiB: K-tile [64 m][64 d] swizzled
  unsigned char* ldsV = smem + 8192;     // 8 KiB: V-tile [64 d][64 m] swizzled
  unsigned char* ldsP = smem + 16384;    // 8 KiB: 4 waves x P [16 q][64 m]

  const int pl    = blockIdx.x >> 6;
  const int qtile = blockIdx.x & 63;
  const int pair  = p0 + pl;
  const int hh = pair >> 2, bb = pair & 3;
  const int t = threadIdx.x;
  const int lane = t & 63, w = t >> 6;
  const int g = lane >> 4, l15 = lane & 15;
  const int q0 = qtile * 64 + w * 16;

  bf16x8 qf[2];
  {
    const unsigned short* qb = Qc + ((size_t)pl * SEQ + q0 + l15) * 64 + g * 8;
    qf[0] = *(const bf16x8*)(qb);
    qf[1] = *(const bf16x8*)(qb + 32);
  }

  f32x4 acc[4];
#pragma unroll
  for (int i = 0; i < 4; ++i) acc[i] = (f32x4){0.f, 0.f, 0.f, 0.f};
  float lsum[4] = {0.f, 0.f, 0.f, 0.f};

  unsigned char* pw = ldsP + w * 2048;

  for (int kt = 0; kt < 64; ++kt) {
    const int m0 = kt * 64;

#pragma unroll
    for (int i = 0; i < 2; ++i) {
      int e = t + (i << 8);
      int row = e >> 3, c16 = e & 7;
      int sw = (c16 * 16) ^ ((row & 7) << 4);
      bf16x8 kv = *(const bf16x8*)(Kc + ((size_t)pl * SEQ + m0 + row) * 64 + c16 * 8);
      *(bf16x8*)(ldsK + row * 128 + sw) = kv;
      bf16x8 vv = *(const bf16x8*)(Vc + ((size_t)pl * 64 + row) * SEQ + m0 + c16 * 8);
      *(bf16x8*)(ldsV + row * 128 + sw) = vv;
    }
    __syncthreads();

    f32x4 sv[4];
#pragma unroll
    for (int cb = 0; cb < 4; ++cb) {
      int mrow = cb * 16 + l15;
      int swb = (mrow & 7) << 4;
      bf16x8 k0 = *(const bf16x8*)(ldsK + mrow * 128 + ((g * 16) ^ swb));
      bf16x8 k1 = *(const bf16x8*)(ldsK + mrow * 128 + ((64 + g * 16) ^ swb));
      f32x4 z = {0.f, 0.f, 0.f, 0.f};
      z = MFMA16(qf[0], k0, z);
      z = MFMA16(qf[1], k1, z);
      sv[cb] = z;
    }

#pragma unroll
    for (int r = 0; r < 4; ++r) {
      int qr = 4 * g + r;
      int swq = (qr & 7) << 4;
#pragma unroll
      for (int cb = 0; cb < 4; ++cb) {
        float p = __expf(sv[cb][r]);
        lsum[r] += p;
        int m = cb * 16 + l15;
        *(unsigned short*)(pw + qr * 128 + ((2 * m) ^ swq)) = f2bf(p);
      }
    }
    __syncthreads();

#pragma unroll
    for (int s = 0; s < 2; ++s) {
      int swp = (l15 & 7) << 4;
      bf16x8 pf = *(const bf16x8*)(pw + l15 * 128 + ((s * 64 + g * 16) ^ swp));
#pragma unroll
      for (int cb = 0; cb < 4; ++cb) {
        int ddr = cb * 16 + l15;
        bf16x8 vf = *(const bf16x8*)(ldsV + ddr * 128 + ((s * 64 + g * 16) ^ ((ddr & 7) << 4)));
        acc[cb] = MFMA16(pf, vf, acc[cb]);
      }
    }
    __syncthreads();
  }

  float rinv[4];
#pragma unroll
  for (int r = 0; r < 4; ++r) {
    float v = lsum[r];
    v += __shfl_xor(v, 1);
    v += __shfl_xor(v, 2);
    v += __shfl_xor(v, 4);
    v += __shfl_xor(v, 8);
    rinv[r] = 1.0f / v;
  }
#pragma unroll
  for (int cb = 0; cb < 4; ++cb)
#pragma unroll
    for (int r = 0; r < 4; ++r)
      acc[cb][r] *= rinv[r];

  // transpose O strip via LDS (q-dim padded to 17) and store
  float* obuf = (float*)(void*)smem + (size_t)w * 1088;
#pragma unroll
  for (int cb = 0; cb < 4; ++cb)
#pragma unroll
    for (int r = 0; r < 4; ++r)
      obuf[(cb * 16 + l15) * 17 + 4 * g + r] = acc[cb][r];
  __syncthreads();

  {
    int dd = lane;
    const float* orow = (const float*)(void*)smem + (size_t)w * 1088 + dd * 17;
    float vals[16];
#pragma unroll
    for (int qq = 0; qq < 16; ++qq) vals[qq] = orow[qq];
    size_t base = ((size_t)(bb * 4 + hh) * 64 + dd) * SEQ + q0;
#pragma unroll
    for (int c4 = 0; c4 < 4; ++c4) {
      f32x4 f = {vals[c4 * 4 + 0], vals[c4 * 4 + 1], vals[c4 * 4 + 2], vals[c4 * 4 + 3]};
      *(f32x4*)(out + base + c4 * 4) = f;
    }
  }
}

// ---------------------------------------------------------------------------
extern "C" void kernel_launch(void* const* d_in, const int* in_sizes, int n_in,
                              void* d_out, int out_size, void* d_ws, size_t ws_size,
                              hipStream_t stream) {
  const float* x  = (const float*)d_in[0];
  const float* y  = (const float*)d_in[1];
  const float* Wq = (const float*)d_in[2];
  const float* bq = (const float*)d_in[3];
  const float* Wk = (const float*)d_in[4];
  const float* bk = (const float*)d_in[5];
  const float* Wv = (const float*)d_in[6];
  const float* bv = (const float*)d_in[7];
  float* o = (float*)d_out;

  // Per pair: Q + K + Vt = 3 x 512 KiB = 1.5 MiB. Choose the largest chunk
  // (np pairs) that fits ws_size; loop chunks on the stream (chunk c's attn
  // finishes before chunk c+1's proj overwrites ws — stream order).
  // ws_size is constant across calls => identical work every call (capture-safe).
  const size_t PER_PAIR = (size_t)3 * SEQ * 64 * sizeof(unsigned short);
  int np = 0;
  if      ((size_t)16 * PER_PAIR <= ws_size) np = 16;
  else if ((size_t) 8 * PER_PAIR <= ws_size) np = 8;
  else if ((size_t) 4 * PER_PAIR <= ws_size) np = 4;
  else if ((size_t) 2 * PER_PAIR <= ws_size) np = 2;
  else if ((size_t) 1 * PER_PAIR <= ws_size) np = 1;
  if (np == 0) return;  // diagnostic: output stays zero => ws_size < 1.5 MiB

  unsigned short* Qc = (unsigned short*)d_ws;
  unsigned short* Kc = Qc + (size_t)np * SEQ * 64;
  unsigned short* Vc = Kc + (size_t)np * SEQ * 64;

  for (int p0 = 0; p0 < 16; p0 += np) {
    proj_tile<<<dim3(np * 64, 3), 256, 0, stream>>>(x, y, Wq, bq, Wk, bk, Wv, bv,
                                                    Qc, Kc, Vc, p0);
    attn_kernel<<<np * 64, 256, 0, stream>>>(Qc, Kc, Vc, o, p0);
  }
}